// Round 2
// baseline (3875.211 us; speedup 1.0000x reference)
//
#include <hip/hip_runtime.h>
#include <hip/hip_bf16.h>
#include <math.h>

// ----------------------------------------------------------------------------
// vMFLunaBlock fp32 baseline v2.
// Shapes: B=4 S=4096 M=256 D=768 H=12 Dh=64 T=S/4=1024 MLP=3072
// Workspace: 38,535,168 floats = 154.1 MB (verified slot-reuse timeline).
// Unpack attention is FUSED (no [B,H,S,M] logits buffer).
// ----------------------------------------------------------------------------

// ---------------- generic batched GEMM ----------------
// C = scale * (A @ op(B)), optional exact-GELU epilogue.
// NT=true : B element (j,k) = B[j*ldb + k]  (weights [N,K], contiguous in k)
// NT=false: B element (k,j) = B[k*ldb + j]  ([K,N], contiguous in j)
// Batched over z = b*HB + h, separate b/h strides on A,B,C.
// Requires M%64==0, N%64==0, K%32==0.
template <bool NT>
__global__ __launch_bounds__(256) void gemm_kernel(
    const float* __restrict__ A, const float* __restrict__ B,
    float* __restrict__ C, int M, int N, int K, int lda, int ldb, int ldc,
    long long aSB, long long aSH, long long bSB, long long bSH,
    long long cSB, long long cSH, int HB, float scale, int gelu) {
  __shared__ float As[32][72];  // [k][m], padded
  __shared__ float Bs[32][72];  // [k][n], padded
  const int z = blockIdx.z;
  const int bb = z / HB, hh = z % HB;
  const float* Ab = A + bb * aSB + hh * aSH;
  const float* Bb = B + bb * bSB + hh * bSH;
  float* Cb = C + bb * cSB + hh * cSH;
  const int row0 = blockIdx.y * 64;
  const int col0 = blockIdx.x * 64;
  const int t = threadIdx.x;
  const int tm = t >> 4, tn = t & 15;

  float acc[4][4] = {};

  for (int k0 = 0; k0 < K; k0 += 32) {
    {  // A tile: 64 rows x 32 k
      const int r = t >> 2, c = (t & 3) * 8;
      const float* s = Ab + (long long)(row0 + r) * lda + (k0 + c);
      const float4 v0 = *(const float4*)s;
      const float4 v1 = *(const float4*)(s + 4);
      As[c + 0][r] = v0.x; As[c + 1][r] = v0.y; As[c + 2][r] = v0.z; As[c + 3][r] = v0.w;
      As[c + 4][r] = v1.x; As[c + 5][r] = v1.y; As[c + 6][r] = v1.z; As[c + 7][r] = v1.w;
    }
    if (NT) {  // B tile: 64 n-rows x 32 k
      const int r = t >> 2, c = (t & 3) * 8;
      const float* s = Bb + (long long)(col0 + r) * ldb + (k0 + c);
      const float4 v0 = *(const float4*)s;
      const float4 v1 = *(const float4*)(s + 4);
      Bs[c + 0][r] = v0.x; Bs[c + 1][r] = v0.y; Bs[c + 2][r] = v0.z; Bs[c + 3][r] = v0.w;
      Bs[c + 4][r] = v1.x; Bs[c + 5][r] = v1.y; Bs[c + 6][r] = v1.z; Bs[c + 7][r] = v1.w;
    } else {  // B tile: 32 k-rows x 64 n (contiguous in n)
      const int kk = t >> 3, j = (t & 7) * 8;
      const float* s = Bb + (long long)(k0 + kk) * ldb + (col0 + j);
      const float4 v0 = *(const float4*)s;
      const float4 v1 = *(const float4*)(s + 4);
      *(float4*)&Bs[kk][j] = v0;
      *(float4*)&Bs[kk][j + 4] = v1;
    }
    __syncthreads();
#pragma unroll
    for (int kk = 0; kk < 32; ++kk) {
      const float4 a4 = *(const float4*)&As[kk][tm * 4];
      const float4 b4 = *(const float4*)&Bs[kk][tn * 4];
      const float av[4] = {a4.x, a4.y, a4.z, a4.w};
      const float bv[4] = {b4.x, b4.y, b4.z, b4.w};
#pragma unroll
      for (int i = 0; i < 4; ++i)
#pragma unroll
        for (int j = 0; j < 4; ++j) acc[i][j] = fmaf(av[i], bv[j], acc[i][j]);
    }
    __syncthreads();
  }

#pragma unroll
  for (int i = 0; i < 4; ++i) {
    float4 o;
    float vv[4];
#pragma unroll
    for (int j = 0; j < 4; ++j) {
      float v = acc[i][j] * scale;
      if (gelu) v = 0.5f * v * (1.f + erff(v * 0.70710678118654752f));
      vv[j] = v;
    }
    o.x = vv[0]; o.y = vv[1]; o.z = vv[2]; o.w = vv[3];
    *(float4*)&Cb[(long long)(row0 + tm * 4 + i) * ldc + (col0 + tn * 4)] = o;
  }
}

// ---------------- grouped conv pool (kernel (4,1), stride (4,1)) ----------------
__global__ __launch_bounds__(256) void conv_pool_kernel(
    const float* __restrict__ in, const float* __restrict__ w,
    float* __restrict__ out, int total, int S, int T) {
  int idx = blockIdx.x * 256 + threadIdx.x;
  if (idx >= total) return;
  const int dh = idx & 63;
  int r = idx >> 6;
  const int tt = r % T; r /= T;
  const int h = r % 12;
  const int b = r / 12;
  const float* s = in + ((long long)b * S + 4 * tt) * 768 + h * 64 + dh;
  const float* wh = w + h * 4;
  out[idx] = fmaf(wh[0], s[0],
             fmaf(wh[1], s[768], fmaf(wh[2], s[1536], wh[3] * s[2304])));
}

// ---------------- row softmax (in place), rowlen = ITERS*256 ----------------
template <int ITERS>
__global__ __launch_bounds__(256) void softmax_kernel(float* __restrict__ data) {
  const long long row = blockIdx.x;
  float* p = data + row * (ITERS * 256);
  const int t = threadIdx.x;
  __shared__ float red[4];
  float v[ITERS];
  float lmax = -3.4e38f;
#pragma unroll
  for (int i = 0; i < ITERS; ++i) {
    v[i] = p[t + (i << 8)];
    lmax = fmaxf(lmax, v[i]);
  }
  for (int o = 32; o; o >>= 1) lmax = fmaxf(lmax, __shfl_xor(lmax, o));
  if ((t & 63) == 0) red[t >> 6] = lmax;
  __syncthreads();
  const float gmax = fmaxf(fmaxf(red[0], red[1]), fmaxf(red[2], red[3]));
  float lsum = 0.f;
#pragma unroll
  for (int i = 0; i < ITERS; ++i) {
    v[i] = expf(v[i] - gmax);
    lsum += v[i];
  }
  __syncthreads();
  for (int o = 32; o; o >>= 1) lsum += __shfl_xor(lsum, o);
  if ((t & 63) == 0) red[t >> 6] = lsum;
  __syncthreads();
  const float inv = 1.f / (red[0] + red[1] + red[2] + red[3]);
#pragma unroll
  for (int i = 0; i < ITERS; ++i) p[t + (i << 8)] = v[i] * inv;
}

// ---------------- fused unpack attention ----------------
// Per block: one (b,h) pair, 64 query rows. 256 keys total, Dh=64.
// out[b, q, h*64+dh] = sum_key softmax_key(q.k/8)[key] * v[key][dh]
// q: [B,4096,768] (head slice h*64); k,v: [B,256,768] (head slice)
__global__ __launch_bounds__(256) void unpack_attn_kernel(
    const float* __restrict__ q, const float* __restrict__ k,
    const float* __restrict__ v, float* __restrict__ out) {
  __shared__ float Ls[64][72];  // [kdim][row] in both phases
  __shared__ float Rs[64][72];  // phase1: [kdim][key]; phase3: [key][dh]
  const int z = blockIdx.z;
  const int b = z / 12, h = z % 12;
  const int row0 = blockIdx.x * 64;
  const int t = threadIdx.x;
  const int tm = t >> 4, tn = t & 15;
  const int r = t >> 2, c0 = (t & 3) * 16;
  const float* qb = q + ((long long)b * 4096 + row0) * 768 + h * 64;
  const float* kb = k + (long long)b * 256 * 768 + h * 64;
  const float* vb = v + (long long)b * 256 * 768 + h * 64;

  float L[4][4][4];  // [key-chunk jc][row i][col j]
  // ---- phase 1: logits (Q tile loaded once, transposed into Ls) ----
  {
    const float* s = qb + (long long)r * 768 + c0;
#pragma unroll
    for (int u = 0; u < 16; ++u) Ls[c0 + u][r] = s[u];
  }
#pragma unroll
  for (int jc = 0; jc < 4; ++jc) {
    __syncthreads();
    {
      const float* s = kb + (long long)(jc * 64 + r) * 768 + c0;
#pragma unroll
      for (int u = 0; u < 16; ++u) Rs[c0 + u][r] = s[u];
    }
    __syncthreads();
    float a00 = 0, a01 = 0, a02 = 0, a03 = 0, a10 = 0, a11 = 0, a12 = 0, a13 = 0,
          a20 = 0, a21 = 0, a22 = 0, a23 = 0, a30 = 0, a31 = 0, a32 = 0, a33 = 0;
#pragma unroll
    for (int kk = 0; kk < 64; ++kk) {
      const float4 a4 = *(const float4*)&Ls[kk][tm * 4];
      const float4 b4 = *(const float4*)&Rs[kk][tn * 4];
      a00 = fmaf(a4.x, b4.x, a00); a01 = fmaf(a4.x, b4.y, a01);
      a02 = fmaf(a4.x, b4.z, a02); a03 = fmaf(a4.x, b4.w, a03);
      a10 = fmaf(a4.y, b4.x, a10); a11 = fmaf(a4.y, b4.y, a11);
      a12 = fmaf(a4.y, b4.z, a12); a13 = fmaf(a4.y, b4.w, a13);
      a20 = fmaf(a4.z, b4.x, a20); a21 = fmaf(a4.z, b4.y, a21);
      a22 = fmaf(a4.z, b4.z, a22); a23 = fmaf(a4.z, b4.w, a23);
      a30 = fmaf(a4.w, b4.x, a30); a31 = fmaf(a4.w, b4.y, a31);
      a32 = fmaf(a4.w, b4.z, a32); a33 = fmaf(a4.w, b4.w, a33);
    }
    L[jc][0][0] = a00; L[jc][0][1] = a01; L[jc][0][2] = a02; L[jc][0][3] = a03;
    L[jc][1][0] = a10; L[jc][1][1] = a11; L[jc][1][2] = a12; L[jc][1][3] = a13;
    L[jc][2][0] = a20; L[jc][2][1] = a21; L[jc][2][2] = a22; L[jc][2][3] = a23;
    L[jc][3][0] = a30; L[jc][3][1] = a31; L[jc][3][2] = a32; L[jc][3][3] = a33;
  }

  // ---- phase 2: softmax over 256 keys (16 regs/row x 16 tn-lanes) ----
#pragma unroll
  for (int i = 0; i < 4; ++i) {
    float m = -3.4e38f;
#pragma unroll
    for (int jc = 0; jc < 4; ++jc)
#pragma unroll
      for (int j = 0; j < 4; ++j) {
        L[jc][i][j] *= 0.125f;
        m = fmaxf(m, L[jc][i][j]);
      }
#pragma unroll
    for (int o = 1; o < 16; o <<= 1) m = fmaxf(m, __shfl_xor(m, o));
    float s = 0.f;
#pragma unroll
    for (int jc = 0; jc < 4; ++jc)
#pragma unroll
      for (int j = 0; j < 4; ++j) {
        L[jc][i][j] = expf(L[jc][i][j] - m);
        s += L[jc][i][j];
      }
#pragma unroll
    for (int o = 1; o < 16; o <<= 1) s += __shfl_xor(s, o);
    const float inv = 1.f / s;
#pragma unroll
    for (int jc = 0; jc < 4; ++jc)
#pragma unroll
      for (int j = 0; j < 4; ++j) L[jc][i][j] *= inv;
  }

  // ---- phase 3: P @ V ----
  float acc[4][4] = {};
#pragma unroll
  for (int jc = 0; jc < 4; ++jc) {
    __syncthreads();
    // P chunk -> Ls[key_local][row]
#pragma unroll
    for (int i = 0; i < 4; ++i)
#pragma unroll
      for (int j = 0; j < 4; ++j) Ls[tn * 4 + j][tm * 4 + i] = L[jc][i][j];
    // V chunk -> Rs[key_local][dh]
    {
      const float* s = vb + (long long)(jc * 64 + r) * 768 + c0;
#pragma unroll
      for (int u = 0; u < 16; u += 4) *(float4*)&Rs[r][c0 + u] = *(const float4*)(s + u);
    }
    __syncthreads();
#pragma unroll
    for (int kk = 0; kk < 64; ++kk) {
      const float4 a4 = *(const float4*)&Ls[kk][tm * 4];
      const float4 b4 = *(const float4*)&Rs[kk][tn * 4];
#pragma unroll
      for (int i = 0; i < 4; ++i) {
        const float av = (i == 0) ? a4.x : (i == 1) ? a4.y : (i == 2) ? a4.z : a4.w;
        acc[i][0] = fmaf(av, b4.x, acc[i][0]);
        acc[i][1] = fmaf(av, b4.y, acc[i][1]);
        acc[i][2] = fmaf(av, b4.z, acc[i][2]);
        acc[i][3] = fmaf(av, b4.w, acc[i][3]);
      }
    }
  }
  float* ob = out + ((long long)b * 4096 + row0) * 768 + h * 64;
#pragma unroll
  for (int i = 0; i < 4; ++i) {
    float4 o;
    o.x = acc[i][0]; o.y = acc[i][1]; o.z = acc[i][2]; o.w = acc[i][3];
    *(float4*)&ob[(long long)(tm * 4 + i) * 768 + tn * 4] = o;
  }
}

// ---------------- LayerNorm(a + b*maskf), eps 1e-6, width 768 ----------------
__global__ __launch_bounds__(256) void ln_kernel(
    const float* __restrict__ a, const float* __restrict__ b,
    const int* __restrict__ mask, float* __restrict__ out) {
  const long long row = blockIdx.x;
  const float* pa = a + row * 768;
  const float* pb = b + row * 768;
  const float ms = mask ? (float)mask[row] : 1.f;
  __shared__ float buf[768];
  __shared__ float red[4];
  const int t = threadIdx.x;
  float lsum = 0.f;
#pragma unroll
  for (int i = t; i < 768; i += 256) {
    const float v = fmaf(pb[i], ms, pa[i]);
    buf[i] = v;
    lsum += v;
  }
  for (int o = 32; o; o >>= 1) lsum += __shfl_xor(lsum, o);
  if ((t & 63) == 0) red[t >> 6] = lsum;
  __syncthreads();
  const float mu = (red[0] + red[1] + red[2] + red[3]) * (1.f / 768.f);
  float lvar = 0.f;
#pragma unroll
  for (int i = t; i < 768; i += 256) {
    const float d = buf[i] - mu;
    lvar = fmaf(d, d, lvar);
  }
  __syncthreads();
  for (int o = 32; o; o >>= 1) lvar += __shfl_xor(lvar, o);
  if ((t & 63) == 0) red[t >> 6] = lvar;
  __syncthreads();
  const float var = (red[0] + red[1] + red[2] + red[3]) * (1.f / 768.f);
  const float rstd = rsqrtf(var + 1e-6f);
  float* po = out + row * 768;
#pragma unroll
  for (int i = t; i < 768; i += 256) po[i] = (buf[i] - mu) * rstd;
}

// ---------------- host ----------------
static inline void gemm_launch(hipStream_t st, bool nt, const float* A,
                               const float* B, float* C, int M, int N, int K,
                               int lda, int ldb, int ldc, long long aSB,
                               long long aSH, long long bSB, long long bSH,
                               long long cSB, long long cSH, int nBat, int HB,
                               float scale, int gelu) {
  dim3 g(N / 64, M / 64, nBat);
  if (nt)
    gemm_kernel<true><<<g, 256, 0, st>>>(A, B, C, M, N, K, lda, ldb, ldc, aSB,
                                         aSH, bSB, bSH, cSB, cSH, HB, scale, gelu);
  else
    gemm_kernel<false><<<g, 256, 0, st>>>(A, B, C, M, N, K, lda, ldb, ldc, aSB,
                                          aSH, bSB, bSH, cSB, cSH, HB, scale, gelu);
}

extern "C" void kernel_launch(void* const* d_in, const int* in_sizes, int n_in,
                              void* d_out, int out_size, void* d_ws,
                              size_t ws_size, hipStream_t stream) {
  const float* x = (const float*)d_in[0];       // [4,4096,768]
  const float* memory = (const float*)d_in[1];  // [4,256,768]
  const int* mask = (const int*)d_in[2];        // [4,4096]
  const float* Wq = (const float*)d_in[3];
  const float* Wk = (const float*)d_in[4];
  const float* Wv = (const float*)d_in[5];
  const float* Wo = (const float*)d_in[6];
  const float* conv_w = (const float*)d_in[7];  // [12,1,4,1]
  const float* Uq = (const float*)d_in[8];
  const float* Uk = (const float*)d_in[9];
  const float* Uv = (const float*)d_in[10];
  const float* Uo = (const float*)d_in[11];
  const float* W1 = (const float*)d_in[12];  // [3072,768]
  const float* W2 = (const float*)d_in[13];  // [768,3072]
  float* out = (float*)d_out;  // q_out [4,4096,768] then m_out [4,256,768]
  float* ws = (float*)d_ws;

  const int Bn = 4, S = 4096, D = 768, H = 12, T = 1024, MLP = 3072;
  const int XR = Bn * S;      // 16384
  const int MR = Bn * 256;    // 1024
  const long long CB = 3145728;  // 4096*768 per-batch chunk

  // workspace slots (floats); total 38,535,168 = 154.1 MB
  float* slotA = ws + 0;         // 12,582,912: kproj -> att -> uattvm -> hbuf
  float* slotB = ws + 12582912;  // 12,582,912: vproj -> uq -> qout1
  float* slotC = ws + 25165824;  //  3,145,728: unp_b / y_b
  float* kp    = ws + 28311552;  //  3,145,728  [B,H,1024,64]
  float* vp    = ws + 31457280;  //  3,145,728
  float* qproj = ws + 34603008;  //    786,432
  float* attvm = ws + 35389440;  //    786,432
  float* packed= ws + 36175872;  //    786,432
  float* ukb   = ws + 36962304;  //    786,432
  float* uvb   = ws + 37748736;  //    786,432

  // ---- pack ----
  gemm_launch(stream, true, x, Wk, slotA, XR, D, D, D, D, D, 0, 0, 0, 0, 0, 0, 1, 1, 1.f, 0);
  gemm_launch(stream, true, x, Wv, slotB, XR, D, D, D, D, D, 0, 0, 0, 0, 0, 0, 1, 1, 1.f, 0);
  gemm_launch(stream, true, memory, Wq, qproj, MR, D, D, D, D, D, 0, 0, 0, 0, 0, 0, 1, 1, 1.f, 0);
  {
    const int total = Bn * H * T * 64;  // 3,145,728
    conv_pool_kernel<<<total / 256, 256, 0, stream>>>(slotA, conv_w, kp, total, S, T);
    conv_pool_kernel<<<total / 256, 256, 0, stream>>>(slotB, conv_w, vp, total, S, T);
  }
  // att (slotA, kproj dead): [B,H,256,1024] = q @ kp^T
  gemm_launch(stream, true, qproj, kp, slotA, 256, 1024, 64, 768, 64, 1024,
              196608, 64, 786432, 65536, 3145728, 262144, Bn * H, H, 1.f, 0);
  softmax_kernel<4><<<Bn * H * 256, 256, 0, stream>>>(slotA);
  gemm_launch(stream, false, slotA, vp, attvm, 256, 64, 1024, 1024, 64, 768,
              3145728, 262144, 786432, 65536, 196608, 64, Bn * H, H, 1.f, 0);
  gemm_launch(stream, true, attvm, Wo, packed, MR, D, D, D, D, D, 0, 0, 0, 0, 0, 0, 1, 1, 1.f, 0);
  // m_out = LN(memory + packed)
  ln_kernel<<<MR, 256, 0, stream>>>(memory, packed, nullptr, out + 12582912);

  // ---- unpack ----
  gemm_launch(stream, true, x, Uq, slotB, XR, D, D, D, D, D, 0, 0, 0, 0, 0, 0, 1, 1, 1.f, 0);  // uq (vproj dead)
  gemm_launch(stream, true, packed, Uk, ukb, MR, D, D, D, D, D, 0, 0, 0, 0, 0, 0, 1, 1, 1.f, 0);
  gemm_launch(stream, true, packed, Uv, uvb, MR, D, D, D, D, D, 0, 0, 0, 0, 0, 0, 1, 1, 1.f, 0);
  // fused attention -> uattvm (slotA, att dead). Mask term is constant per
  // softmax row -> provably a no-op; masked rows are zeroed via LN input.
  {
    dim3 g(S / 64, 1, Bn * H);
    unpack_attn_kernel<<<g, 256, 0, stream>>>(slotB, ukb, uvb, slotA);
  }
  // per batch: unp_b = uattvm_b @ Uo^T ; qout1_b = LN(x_b + unp_b * mask_b)
  for (int b = 0; b < Bn; ++b) {
    gemm_launch(stream, true, slotA + b * CB, Uo, slotC, S, D, D, D, D, D,
                0, 0, 0, 0, 0, 0, 1, 1, 1.f, 0);
    ln_kernel<<<S, 256, 0, stream>>>(x + b * CB, slotC, mask + b * S, slotB + b * CB);
  }
  // ---- FFN per batch (slotA free: uattvm dead) ----
  for (int b = 0; b < Bn; ++b) {
    gemm_launch(stream, true, slotB + b * CB, W1, slotA, S, MLP, D, D, D, MLP,
                0, 0, 0, 0, 0, 0, 1, 1, 1.f, 1);
    gemm_launch(stream, true, slotA, W2, slotC, S, D, MLP, MLP, MLP, D,
                0, 0, 0, 0, 0, 0, 1, 1, 1.f, 0);
    ln_kernel<<<S, 256, 0, stream>>>(slotB + b * CB, slotC, mask + b * S, out + b * CB);
  }
}

// Round 3
// 1947.350 us; speedup vs baseline: 1.9900x; 1.9900x over previous
//
#include <hip/hip_runtime.h>
#include <hip/hip_bf16.h>
#include <math.h>

// ----------------------------------------------------------------------------
// vMFLunaBlock v3: split-bf16 (hi/lo) MFMA GEMMs for all big NT matmuls.
// Shapes: B=4 S=4096 M=256 D=768 H=12 Dh=64 T=1024 MLP=3072
// Accuracy: 3-term split product (Ah*Bh + Ah*Bl + Al*Bh) ~ 2^-16 relative.
// Workspace: 40,894,464 floats = 163.6 MB (slot timeline audited below).
// ----------------------------------------------------------------------------

typedef unsigned short u16;
typedef __attribute__((ext_vector_type(8))) short bf8v;   // 8 bf16 (4 VGPR)
typedef __attribute__((ext_vector_type(4))) float f4v;
typedef __attribute__((ext_vector_type(4))) unsigned short us4v;

#define AS1 __attribute__((address_space(1)))
#define AS3 __attribute__((address_space(3)))

__device__ __forceinline__ void gld_lds16(const void* g, void* l) {
  __builtin_amdgcn_global_load_lds((const AS1 unsigned int*)g,
                                   (AS3 unsigned int*)l, 16, 0, 0);
}

__device__ __forceinline__ u16 bf16_rne(float x) {
  unsigned u = __float_as_uint(x);
  return (u16)((u + 0x7fffu + ((u >> 16) & 1u)) >> 16);
}
__device__ __forceinline__ float bf16_to_f(u16 h) {
  return __uint_as_float(((unsigned)h) << 16);
}

// ---------------- split fp32 -> (hi, lo) bf16 ----------------
__global__ __launch_bounds__(256) void split_kernel(
    const float* __restrict__ in, u16* __restrict__ hi, u16* __restrict__ lo,
    int n4) {
  int i = blockIdx.x * 256 + threadIdx.x;
  if (i >= n4) return;
  float4 v = ((const float4*)in)[i];
  us4v h, l;
  float vv[4] = {v.x, v.y, v.z, v.w};
#pragma unroll
  for (int j = 0; j < 4; ++j) {
    u16 hb = bf16_rne(vv[j]);
    h[j] = hb;
    l[j] = bf16_rne(vv[j] - bf16_to_f(hb));
  }
  ((us4v*)hi)[i] = h;
  ((us4v*)lo)[i] = l;
}

// ---------------- split-bf16 MFMA GEMM ----------------
// C = scale * (A @ B^T)  [+ exact GELU]
// A: fp32 [M x K] (lda), split to hi/lo in-kernel (reg-staged).
// B: pre-split bf16 hi/lo arrays, [N x K] layout (ldb).
// Tiles: 128x128, BK=32. 4 waves, each computes 64x64 via 4x4 16x16x32 frags.
// LDS tiles [128][32] u16; chunk-XOR swizzle (c ^= row bits 1:2) both sides.
template <int GELU>
__global__ __launch_bounds__(256) void mgemm_kernel(
    const float* __restrict__ A, const u16* __restrict__ Bh,
    const u16* __restrict__ Bl, float* __restrict__ C, int M, int N, int K,
    int lda, int ldb, int ldc, float scale) {
  __shared__ u16 sm[4][4096];  // 0:Ahi 1:Alo 2:Bhi 3:Blo, each [128][32]
  const int t = threadIdx.x;
  const int w = t >> 6, lane = t & 63;
  const int row0 = blockIdx.y * 128, col0 = blockIdx.x * 128;

  // B staging (gload_lds): issue g = w*4+i; matrix 2+(g>>3), 16-row group g&7
  const int brow_l = lane >> 2;                       // row within group
  const int bchunk = ((lane & 3) ^ ((lane >> 3) & 3)) * 8;  // swizzled src col
  // A staging (reg): round i: row = i*32 + (t>>3), col = (t&7)*4
  const int ar = t >> 3;
  const int ac = (t & 7) * 4;
  const int adst = ((((t >> 1) & 3) ^ ((t >> 4) & 3)) * 8) + ((t & 1) * 4);
  // fragment reads
  const int fr = lane & 15;                  // row within fragment
  const int fq = lane >> 4;                  // k-group / C reg-group
  const int fco = (fq ^ ((lane >> 1) & 3)) * 8;  // swizzled col offset
  const int wr = (w >> 1) * 64, wc = (w & 1) * 64;

  f4v acc[4][4];
#pragma unroll
  for (int i = 0; i < 4; ++i)
#pragma unroll
    for (int j = 0; j < 4; ++j) acc[i][j] = {0.f, 0.f, 0.f, 0.f};

  for (int k0 = 0; k0 < K; k0 += 32) {
    __syncthreads();
    // ---- B: async global -> LDS (16B, linear dest, pre-swizzled source) ----
#pragma unroll
    for (int i = 0; i < 4; ++i) {
      const int g = w * 4 + i;
      const int hl = g >> 3, ms = g & 7;
      const int r = ms * 16 + brow_l;
      const u16* src =
          (hl ? Bl : Bh) + (long long)(col0 + r) * ldb + k0 + bchunk;
      gld_lds16(src, &sm[2 + hl][ms * 512 + lane * 8]);
    }
    // ---- A: fp32 load -> split -> swizzled ds_write ----
#pragma unroll
    for (int i = 0; i < 4; ++i) {
      const int r = i * 32 + ar;
      const float4 v = *(const float4*)(A + (long long)(row0 + r) * lda + k0 + ac);
      const float vv[4] = {v.x, v.y, v.z, v.w};
      us4v h, l;
#pragma unroll
      for (int j = 0; j < 4; ++j) {
        u16 hb = bf16_rne(vv[j]);
        h[j] = hb;
        l[j] = bf16_rne(vv[j] - bf16_to_f(hb));
      }
      *(us4v*)&sm[0][r * 32 + adst] = h;
      *(us4v*)&sm[1][r * 32 + adst] = l;
    }
    __syncthreads();
    // ---- fragments ----
    bf8v af[4][2], bf[4][2];
#pragma unroll
    for (int mi = 0; mi < 4; ++mi) {
      const int r = wr + mi * 16 + fr;
      af[mi][0] = *(const bf8v*)&sm[0][r * 32 + fco];
      af[mi][1] = *(const bf8v*)&sm[1][r * 32 + fco];
    }
#pragma unroll
    for (int nj = 0; nj < 4; ++nj) {
      const int r = wc + nj * 16 + fr;
      bf[nj][0] = *(const bf8v*)&sm[2][r * 32 + fco];
      bf[nj][1] = *(const bf8v*)&sm[3][r * 32 + fco];
    }
#pragma unroll
    for (int mi = 0; mi < 4; ++mi)
#pragma unroll
      for (int nj = 0; nj < 4; ++nj) {
        acc[mi][nj] = __builtin_amdgcn_mfma_f32_16x16x32_bf16(
            af[mi][0], bf[nj][0], acc[mi][nj], 0, 0, 0);
        acc[mi][nj] = __builtin_amdgcn_mfma_f32_16x16x32_bf16(
            af[mi][0], bf[nj][1], acc[mi][nj], 0, 0, 0);
        acc[mi][nj] = __builtin_amdgcn_mfma_f32_16x16x32_bf16(
            af[mi][1], bf[nj][0], acc[mi][nj], 0, 0, 0);
      }
  }
  // ---- epilogue: C/D layout col = lane&15, row = (lane>>4)*4 + reg ----
#pragma unroll
  for (int mi = 0; mi < 4; ++mi)
#pragma unroll
    for (int nj = 0; nj < 4; ++nj) {
      const int col = col0 + wc + nj * 16 + fr;
      const long long base =
          (long long)(row0 + wr + mi * 16 + fq * 4) * ldc + col;
#pragma unroll
      for (int j = 0; j < 4; ++j) {
        float v = acc[mi][nj][j] * scale;
        if (GELU) v = 0.5f * v * (1.f + erff(v * 0.70710678118654752f));
        C[base + (long long)j * ldc] = v;
      }
    }
}

// ---------------- fp32 batched GEMM (kept for small attention matmuls) ----
template <bool NT>
__global__ __launch_bounds__(256) void gemm_kernel(
    const float* __restrict__ A, const float* __restrict__ B,
    float* __restrict__ C, int M, int N, int K, int lda, int ldb, int ldc,
    long long aSB, long long aSH, long long bSB, long long bSH,
    long long cSB, long long cSH, int HB, float scale, int gelu) {
  __shared__ float As[32][72];
  __shared__ float Bs[32][72];
  const int z = blockIdx.z;
  const int bb = z / HB, hh = z % HB;
  const float* Ab = A + bb * aSB + hh * aSH;
  const float* Bb = B + bb * bSB + hh * bSH;
  float* Cb = C + bb * cSB + hh * cSH;
  const int row0 = blockIdx.y * 64;
  const int col0 = blockIdx.x * 64;
  const int t = threadIdx.x;
  const int tm = t >> 4, tn = t & 15;

  float acc[4][4] = {};

  for (int k0 = 0; k0 < K; k0 += 32) {
    {
      const int r = t >> 2, c = (t & 3) * 8;
      const float* s = Ab + (long long)(row0 + r) * lda + (k0 + c);
      const float4 v0 = *(const float4*)s;
      const float4 v1 = *(const float4*)(s + 4);
      As[c + 0][r] = v0.x; As[c + 1][r] = v0.y; As[c + 2][r] = v0.z; As[c + 3][r] = v0.w;
      As[c + 4][r] = v1.x; As[c + 5][r] = v1.y; As[c + 6][r] = v1.z; As[c + 7][r] = v1.w;
    }
    if (NT) {
      const int r = t >> 2, c = (t & 3) * 8;
      const float* s = Bb + (long long)(col0 + r) * ldb + (k0 + c);
      const float4 v0 = *(const float4*)s;
      const float4 v1 = *(const float4*)(s + 4);
      Bs[c + 0][r] = v0.x; Bs[c + 1][r] = v0.y; Bs[c + 2][r] = v0.z; Bs[c + 3][r] = v0.w;
      Bs[c + 4][r] = v1.x; Bs[c + 5][r] = v1.y; Bs[c + 6][r] = v1.z; Bs[c + 7][r] = v1.w;
    } else {
      const int kk = t >> 3, j = (t & 7) * 8;
      const float* s = Bb + (long long)(k0 + kk) * ldb + (col0 + j);
      const float4 v0 = *(const float4*)s;
      const float4 v1 = *(const float4*)(s + 4);
      *(float4*)&Bs[kk][j] = v0;
      *(float4*)&Bs[kk][j + 4] = v1;
    }
    __syncthreads();
#pragma unroll
    for (int kk = 0; kk < 32; ++kk) {
      const float4 a4 = *(const float4*)&As[kk][tm * 4];
      const float4 b4 = *(const float4*)&Bs[kk][tn * 4];
      const float av[4] = {a4.x, a4.y, a4.z, a4.w};
      const float bv[4] = {b4.x, b4.y, b4.z, b4.w};
#pragma unroll
      for (int i = 0; i < 4; ++i)
#pragma unroll
        for (int j = 0; j < 4; ++j) acc[i][j] = fmaf(av[i], bv[j], acc[i][j]);
    }
    __syncthreads();
  }

#pragma unroll
  for (int i = 0; i < 4; ++i) {
    float4 o;
    float vv[4];
#pragma unroll
    for (int j = 0; j < 4; ++j) {
      float v = acc[i][j] * scale;
      if (gelu) v = 0.5f * v * (1.f + erff(v * 0.70710678118654752f));
      vv[j] = v;
    }
    o.x = vv[0]; o.y = vv[1]; o.z = vv[2]; o.w = vv[3];
    *(float4*)&Cb[(long long)(row0 + tm * 4 + i) * ldc + (col0 + tn * 4)] = o;
  }
}

// ---------------- grouped conv pool ----------------
__global__ __launch_bounds__(256) void conv_pool_kernel(
    const float* __restrict__ in, const float* __restrict__ w,
    float* __restrict__ out, int total, int S, int T) {
  int idx = blockIdx.x * 256 + threadIdx.x;
  if (idx >= total) return;
  const int dh = idx & 63;
  int r = idx >> 6;
  const int tt = r % T; r /= T;
  const int h = r % 12;
  const int b = r / 12;
  const float* s = in + ((long long)b * S + 4 * tt) * 768 + h * 64 + dh;
  const float* wh = w + h * 4;
  out[idx] = fmaf(wh[0], s[0],
             fmaf(wh[1], s[768], fmaf(wh[2], s[1536], wh[3] * s[2304])));
}

// ---------------- row softmax (in place) ----------------
template <int ITERS>
__global__ __launch_bounds__(256) void softmax_kernel(float* __restrict__ data) {
  const long long row = blockIdx.x;
  float* p = data + row * (ITERS * 256);
  const int t = threadIdx.x;
  __shared__ float red[4];
  float v[ITERS];
  float lmax = -3.4e38f;
#pragma unroll
  for (int i = 0; i < ITERS; ++i) {
    v[i] = p[t + (i << 8)];
    lmax = fmaxf(lmax, v[i]);
  }
  for (int o = 32; o; o >>= 1) lmax = fmaxf(lmax, __shfl_xor(lmax, o));
  if ((t & 63) == 0) red[t >> 6] = lmax;
  __syncthreads();
  const float gmax = fmaxf(fmaxf(red[0], red[1]), fmaxf(red[2], red[3]));
  float lsum = 0.f;
#pragma unroll
  for (int i = 0; i < ITERS; ++i) {
    v[i] = expf(v[i] - gmax);
    lsum += v[i];
  }
  __syncthreads();
  for (int o = 32; o; o >>= 1) lsum += __shfl_xor(lsum, o);
  if ((t & 63) == 0) red[t >> 6] = lsum;
  __syncthreads();
  const float inv = 1.f / (red[0] + red[1] + red[2] + red[3]);
#pragma unroll
  for (int i = 0; i < ITERS; ++i) p[t + (i << 8)] = v[i] * inv;
}

// ---------------- fused unpack attention ----------------
__global__ __launch_bounds__(256) void unpack_attn_kernel(
    const float* __restrict__ q, const float* __restrict__ k,
    const float* __restrict__ v, float* __restrict__ out) {
  __shared__ float Ls[64][72];
  __shared__ float Rs[64][72];
  const int z = blockIdx.z;
  const int b = z / 12, h = z % 12;
  const int row0 = blockIdx.x * 64;
  const int t = threadIdx.x;
  const int tm = t >> 4, tn = t & 15;
  const int r = t >> 2, c0 = (t & 3) * 16;
  const float* qb = q + ((long long)b * 4096 + row0) * 768 + h * 64;
  const float* kb = k + (long long)b * 256 * 768 + h * 64;
  const float* vb = v + (long long)b * 256 * 768 + h * 64;

  float L[4][4][4];
  {
    const float* s = qb + (long long)r * 768 + c0;
#pragma unroll
    for (int u = 0; u < 16; ++u) Ls[c0 + u][r] = s[u];
  }
#pragma unroll
  for (int jc = 0; jc < 4; ++jc) {
    __syncthreads();
    {
      const float* s = kb + (long long)(jc * 64 + r) * 768 + c0;
#pragma unroll
      for (int u = 0; u < 16; ++u) Rs[c0 + u][r] = s[u];
    }
    __syncthreads();
    float a00 = 0, a01 = 0, a02 = 0, a03 = 0, a10 = 0, a11 = 0, a12 = 0, a13 = 0,
          a20 = 0, a21 = 0, a22 = 0, a23 = 0, a30 = 0, a31 = 0, a32 = 0, a33 = 0;
#pragma unroll
    for (int kk = 0; kk < 64; ++kk) {
      const float4 a4 = *(const float4*)&Ls[kk][tm * 4];
      const float4 b4 = *(const float4*)&Rs[kk][tn * 4];
      a00 = fmaf(a4.x, b4.x, a00); a01 = fmaf(a4.x, b4.y, a01);
      a02 = fmaf(a4.x, b4.z, a02); a03 = fmaf(a4.x, b4.w, a03);
      a10 = fmaf(a4.y, b4.x, a10); a11 = fmaf(a4.y, b4.y, a11);
      a12 = fmaf(a4.y, b4.z, a12); a13 = fmaf(a4.y, b4.w, a13);
      a20 = fmaf(a4.z, b4.x, a20); a21 = fmaf(a4.z, b4.y, a21);
      a22 = fmaf(a4.z, b4.z, a22); a23 = fmaf(a4.z, b4.w, a23);
      a30 = fmaf(a4.w, b4.x, a30); a31 = fmaf(a4.w, b4.y, a31);
      a32 = fmaf(a4.w, b4.z, a32); a33 = fmaf(a4.w, b4.w, a33);
    }
    L[jc][0][0] = a00; L[jc][0][1] = a01; L[jc][0][2] = a02; L[jc][0][3] = a03;
    L[jc][1][0] = a10; L[jc][1][1] = a11; L[jc][1][2] = a12; L[jc][1][3] = a13;
    L[jc][2][0] = a20; L[jc][2][1] = a21; L[jc][2][2] = a22; L[jc][2][3] = a23;
    L[jc][3][0] = a30; L[jc][3][1] = a31; L[jc][3][2] = a32; L[jc][3][3] = a33;
  }

#pragma unroll
  for (int i = 0; i < 4; ++i) {
    float m = -3.4e38f;
#pragma unroll
    for (int jc = 0; jc < 4; ++jc)
#pragma unroll
      for (int j = 0; j < 4; ++j) {
        L[jc][i][j] *= 0.125f;
        m = fmaxf(m, L[jc][i][j]);
      }
#pragma unroll
    for (int o = 1; o < 16; o <<= 1) m = fmaxf(m, __shfl_xor(m, o));
    float s = 0.f;
#pragma unroll
    for (int jc = 0; jc < 4; ++jc)
#pragma unroll
      for (int j = 0; j < 4; ++j) {
        L[jc][i][j] = expf(L[jc][i][j] - m);
        s += L[jc][i][j];
      }
#pragma unroll
    for (int o = 1; o < 16; o <<= 1) s += __shfl_xor(s, o);
    const float inv = 1.f / s;
#pragma unroll
    for (int jc = 0; jc < 4; ++jc)
#pragma unroll
      for (int j = 0; j < 4; ++j) L[jc][i][j] *= inv;
  }

  float acc[4][4] = {};
#pragma unroll
  for (int jc = 0; jc < 4; ++jc) {
    __syncthreads();
#pragma unroll
    for (int i = 0; i < 4; ++i)
#pragma unroll
      for (int j = 0; j < 4; ++j) Ls[tn * 4 + j][tm * 4 + i] = L[jc][i][j];
    {
      const float* s = vb + (long long)(jc * 64 + r) * 768 + c0;
#pragma unroll
      for (int u = 0; u < 16; u += 4) *(float4*)&Rs[r][c0 + u] = *(const float4*)(s + u);
    }
    __syncthreads();
#pragma unroll
    for (int kk = 0; kk < 64; ++kk) {
      const float4 a4 = *(const float4*)&Ls[kk][tm * 4];
      const float4 b4 = *(const float4*)&Rs[kk][tn * 4];
#pragma unroll
      for (int i = 0; i < 4; ++i) {
        const float av = (i == 0) ? a4.x : (i == 1) ? a4.y : (i == 2) ? a4.z : a4.w;
        acc[i][0] = fmaf(av, b4.x, acc[i][0]);
        acc[i][1] = fmaf(av, b4.y, acc[i][1]);
        acc[i][2] = fmaf(av, b4.z, acc[i][2]);
        acc[i][3] = fmaf(av, b4.w, acc[i][3]);
      }
    }
  }
  float* ob = out + ((long long)b * 4096 + row0) * 768 + h * 64;
#pragma unroll
  for (int i = 0; i < 4; ++i) {
    float4 o;
    o.x = acc[i][0]; o.y = acc[i][1]; o.z = acc[i][2]; o.w = acc[i][3];
    *(float4*)&ob[(long long)(tm * 4 + i) * 768 + tn * 4] = o;
  }
}

// ---------------- LayerNorm(a + b*maskf), eps 1e-6, width 768 ----------------
__global__ __launch_bounds__(256) void ln_kernel(
    const float* __restrict__ a, const float* __restrict__ b,
    const int* __restrict__ mask, float* __restrict__ out) {
  const long long row = blockIdx.x;
  const float* pa = a + row * 768;
  const float* pb = b + row * 768;
  const float ms = mask ? (float)mask[row] : 1.f;
  __shared__ float buf[768];
  __shared__ float red[4];
  const int t = threadIdx.x;
  float lsum = 0.f;
#pragma unroll
  for (int i = t; i < 768; i += 256) {
    const float v = fmaf(pb[i], ms, pa[i]);
    buf[i] = v;
    lsum += v;
  }
  for (int o = 32; o; o >>= 1) lsum += __shfl_xor(lsum, o);
  if ((t & 63) == 0) red[t >> 6] = lsum;
  __syncthreads();
  const float mu = (red[0] + red[1] + red[2] + red[3]) * (1.f / 768.f);
  float lvar = 0.f;
#pragma unroll
  for (int i = t; i < 768; i += 256) {
    const float d = buf[i] - mu;
    lvar = fmaf(d, d, lvar);
  }
  __syncthreads();
  for (int o = 32; o; o >>= 1) lvar += __shfl_xor(lvar, o);
  if ((t & 63) == 0) red[t >> 6] = lvar;
  __syncthreads();
  const float var = (red[0] + red[1] + red[2] + red[3]) * (1.f / 768.f);
  const float rstd = rsqrtf(var + 1e-6f);
  float* po = out + row * 768;
#pragma unroll
  for (int i = t; i < 768; i += 256) po[i] = (buf[i] - mu) * rstd;
}

// ---------------- host helpers ----------------
static inline void gemm_launch(hipStream_t st, bool nt, const float* A,
                               const float* B, float* C, int M, int N, int K,
                               int lda, int ldb, int ldc, long long aSB,
                               long long aSH, long long bSB, long long bSH,
                               long long cSB, long long cSH, int nBat, int HB,
                               float scale, int gelu) {
  dim3 g(N / 64, M / 64, nBat);
  if (nt)
    gemm_kernel<true><<<g, 256, 0, st>>>(A, B, C, M, N, K, lda, ldb, ldc, aSB,
                                         aSH, bSB, bSH, cSB, cSH, HB, scale, gelu);
  else
    gemm_kernel<false><<<g, 256, 0, st>>>(A, B, C, M, N, K, lda, ldb, ldc, aSB,
                                          aSH, bSB, bSH, cSB, cSH, HB, scale, gelu);
}

static inline void mgemm_launch(hipStream_t st, const float* A, const u16* Bh,
                                const u16* Bl, float* C, int M, int N, int K,
                                int lda, int ldb, int ldc, int gelu) {
  dim3 g(N / 128, M / 128, 1);
  if (gelu)
    mgemm_kernel<1><<<g, 256, 0, st>>>(A, Bh, Bl, C, M, N, K, lda, ldb, ldc, 1.f);
  else
    mgemm_kernel<0><<<g, 256, 0, st>>>(A, Bh, Bl, C, M, N, K, lda, ldb, ldc, 1.f);
}

static inline void split_launch(hipStream_t st, const float* in, u16* hi,
                                u16* lo, int n) {
  int n4 = n / 4;
  split_kernel<<<(n4 + 255) / 256, 256, 0, st>>>(in, hi, lo, n4);
}

extern "C" void kernel_launch(void* const* d_in, const int* in_sizes, int n_in,
                              void* d_out, int out_size, void* d_ws,
                              size_t ws_size, hipStream_t stream) {
  const float* x = (const float*)d_in[0];       // [4,4096,768]
  const float* memory = (const float*)d_in[1];  // [4,256,768]
  const int* mask = (const int*)d_in[2];        // [4,4096]
  const float* Wq = (const float*)d_in[3];
  const float* Wk = (const float*)d_in[4];
  const float* Wv = (const float*)d_in[5];
  const float* Wo = (const float*)d_in[6];
  const float* conv_w = (const float*)d_in[7];  // [12,1,4,1]
  const float* Uq = (const float*)d_in[8];
  const float* Uk = (const float*)d_in[9];
  const float* Uv = (const float*)d_in[10];
  const float* Uo = (const float*)d_in[11];
  const float* W1 = (const float*)d_in[12];  // [3072,768]
  const float* W2 = (const float*)d_in[13];  // [768,3072]
  float* out = (float*)d_out;  // q_out [4,4096,768] then m_out [4,256,768]
  float* ws = (float*)d_ws;

  const int Bn = 4, S = 4096, D = 768, H = 12, T = 1024, MLP = 3072;
  const int XR = Bn * S;      // 16384
  const int MR = Bn * 256;    // 1024
  const long long CB = 3145728;  // 4096*768
  const int WD = 589824;      // 768*768

  // ---- workspace (float units); total 40,894,464 = 163.6 MB ----
  float* slotA = ws + 0;         // 12,582,912: kproj -> att -> uattvm -> hbuf
  float* slotB = ws + 12582912;  // 12,582,912: vproj -> uq -> qout1(f32)
  float* slotC = ws + 25165824;  //  3,145,728: unp_b / y_b
  float* X     = ws + 28311552;  //  6,291,456: kp+vp -> U-splits -> W1/W2 splits
  float* qproj = ws + 34603008;  //    786,432
  float* attvm = ws + 35389440;  //    786,432
  float* packed= ws + 36175872;  //    786,432
  float* ukb   = ws + 36962304;  //    786,432
  float* uvb   = ws + 37748736;  //    786,432
  float* Wp    = ws + 38535168;  //  2,359,296: pack-weight splits (u16 x 4,718,592)

  float* kp = X;                 // [B,H,1024,64]
  float* vp = X + 3145728;

  u16* wp16 = (u16*)Wp;
  u16 *Wkh = wp16, *Wkl = wp16 + WD, *Wvh = wp16 + 2 * WD, *Wvl = wp16 + 3 * WD,
      *Wqh = wp16 + 4 * WD, *Wql = wp16 + 5 * WD, *Woh = wp16 + 6 * WD,
      *Wol = wp16 + 7 * WD;
  u16* x16 = (u16*)X;  // U splits / W1,W2 splits (time-shared with kp/vp)
  u16 *Uqh = x16, *Uql = x16 + WD, *Ukh = x16 + 2 * WD, *Ukl = x16 + 3 * WD,
      *Uvh = x16 + 4 * WD, *Uvl = x16 + 5 * WD, *Uoh = x16 + 6 * WD,
      *Uol = x16 + 7 * WD;
  const int WM = 2359296;  // 3072*768
  u16 *W1h = x16, *W1l = x16 + WM, *W2h = x16 + 2 * WM, *W2l = x16 + 3 * WM;

  // ---- pack phase ----
  split_launch(stream, Wk, Wkh, Wkl, WD);
  split_launch(stream, Wv, Wvh, Wvl, WD);
  split_launch(stream, Wq, Wqh, Wql, WD);
  split_launch(stream, Wo, Woh, Wol, WD);
  mgemm_launch(stream, x, Wkh, Wkl, slotA, XR, D, D, D, D, D, 0);      // kproj
  mgemm_launch(stream, x, Wvh, Wvl, slotB, XR, D, D, D, D, D, 0);      // vproj
  mgemm_launch(stream, memory, Wqh, Wql, qproj, MR, D, D, D, D, D, 0); // qproj
  {
    const int total = Bn * H * T * 64;
    conv_pool_kernel<<<total / 256, 256, 0, stream>>>(slotA, conv_w, kp, total, S, T);
    conv_pool_kernel<<<total / 256, 256, 0, stream>>>(slotB, conv_w, vp, total, S, T);
  }
  // pack logits [B,H,256,1024] = q @ kp^T  (fp32, K=64, bh-batched)
  gemm_launch(stream, true, qproj, kp, slotA, 256, 1024, 64, 768, 64, 1024,
              196608, 64, 786432, 65536, 3145728, 262144, Bn * H, H, 1.f, 0);
  softmax_kernel<4><<<Bn * H * 256, 256, 0, stream>>>(slotA);
  gemm_launch(stream, false, slotA, vp, attvm, 256, 64, 1024, 1024, 64, 768,
              3145728, 262144, 786432, 65536, 196608, 64, Bn * H, H, 1.f, 0);
  mgemm_launch(stream, attvm, Woh, Wol, packed, MR, D, D, D, D, D, 0);  // packed
  ln_kernel<<<MR, 256, 0, stream>>>(memory, packed, nullptr, out + 12582912);

  // ---- unpack phase (kp/vp dead -> X hosts U splits) ----
  split_launch(stream, Uq, Uqh, Uql, WD);
  split_launch(stream, Uk, Ukh, Ukl, WD);
  split_launch(stream, Uv, Uvh, Uvl, WD);
  split_launch(stream, Uo, Uoh, Uol, WD);
  mgemm_launch(stream, x, Uqh, Uql, slotB, XR, D, D, D, D, D, 0);       // uq
  mgemm_launch(stream, packed, Ukh, Ukl, ukb, MR, D, D, D, D, D, 0);
  mgemm_launch(stream, packed, Uvh, Uvl, uvb, MR, D, D, D, D, D, 0);
  {
    dim3 g(S / 64, 1, Bn * H);
    unpack_attn_kernel<<<g, 256, 0, stream>>>(slotB, ukb, uvb, slotA);  // uattvm
  }
  for (int b = 0; b < Bn; ++b) {
    mgemm_launch(stream, slotA + b * CB, Uoh, Uol, slotC, S, D, D, D, D, D, 0);
    ln_kernel<<<S, 256, 0, stream>>>(x + b * CB, slotC, mask + b * S, slotB + b * CB);
  }

  // ---- FFN phase (U splits dead -> X hosts W1/W2 splits) ----
  split_launch(stream, W1, W1h, W1l, WM);
  split_launch(stream, W2, W2h, W2l, WM);
  for (int b = 0; b < Bn; ++b) {
    mgemm_launch(stream, slotB + b * CB, W1h, W1l, slotA, S, MLP, D, D, D, MLP, 1);
    mgemm_launch(stream, slotA, W2h, W2l, slotC, S, D, MLP, MLP, MLP, D, 0);
    ln_kernel<<<S, 256, 0, stream>>>(slotB + b * CB, slotC, mask + b * S, out + b * CB);
  }
}